// Round 8
// baseline (109.740 us; speedup 1.0000x reference)
//
#include <hip/hip_runtime.h>
#include <math.h>

#define SEQ   64
#define DIM   512
#define NOSC  14
#define NSTEP 100
#define RPB   4     // rows per block = waves per block (1 row per wave)

typedef float f4 __attribute__((ext_vector_type(4)));

// DPP sums (bound_ctrl=1). Patterns are local to each 16-lane row, so four
// independent 16-lane reductions coexist in one 64-lane wave.
__device__ __forceinline__ float dpp_sum4(float v) {   // sum within quad
    v += __int_as_float(__builtin_amdgcn_update_dpp(0, __float_as_int(v), 0xB1,  0xF, 0xF, true));
    v += __int_as_float(__builtin_amdgcn_update_dpp(0, __float_as_int(v), 0x4E,  0xF, 0xF, true));
    return v;
}
__device__ __forceinline__ float dpp_sum16(float v) {  // sum within 16-lane row
    v += __int_as_float(__builtin_amdgcn_update_dpp(0, __float_as_int(v), 0xB1,  0xF, 0xF, true));
    v += __int_as_float(__builtin_amdgcn_update_dpp(0, __float_as_int(v), 0x4E,  0xF, 0xF, true));
    v += __int_as_float(__builtin_amdgcn_update_dpp(0, __float_as_int(v), 0x141, 0xF, 0xF, true));
    v += __int_as_float(__builtin_amdgcn_update_dpp(0, __float_as_int(v), 0x140, 0xF, 0xF, true));
    return v;
}

// HW trig: v_sin_f32 / v_cos_f32 take REVOLUTIONS; reduce with fract first.
__device__ __forceinline__ void fast_sincos(float theta, float* s, float* c) {
    const float inv2pi = 0.15915494309189535f;
    float r = theta * inv2pi;
    r = r - floorf(r);
    *s = __builtin_amdgcn_sinf(r);
    *c = __builtin_amdgcn_cosf(r);
}

// Fully wave-independent: each 64-lane wave owns ONE row end-to-end.
// R8 A/B: identical to R7 except PLAIN loads (no nontemporal hint).
__global__ __launch_bounds__(256, 4)
void fused_kernel(const float* __restrict__ x,
                  const float* __restrict__ W_in,
                  const float* __restrict__ b_in,
                  const float* __restrict__ omega,
                  const float* __restrict__ Wc,
                  const float* __restrict__ bc,
                  float* __restrict__ out, int B)
{
    const int t   = threadIdx.x;
    const int wv  = t >> 6;
    const int ln  = t & 63;
    const int row = blockIdx.x * RPB + wv;

    __shared__ f4    mv[RPB][DIM / 4];   // per-wave private pooled row
    __shared__ float th0[RPB][16];       // per-wave theta0

    if (row >= B) return;                // uniform per wave

    // ---- load + pool: this wave reads its whole row (2 x f4 per token) ----
    const f4* xv = reinterpret_cast<const f4*>(x + (size_t)row * (SEQ * DIM));
    f4 a0 = (f4)(0.0f), a1 = (f4)(0.0f);
#pragma unroll 8
    for (int s = 0; s < SEQ; ++s) {
        a0 += xv[s * (DIM / 4) + ln];
        a1 += xv[s * (DIM / 4) + 64 + ln];
    }
    f4* mw = mv[wv];
    mw[ln]      = a0 * (1.0f / SEQ);
    mw[ln + 64] = a1 * (1.0f / SEQ);
    asm volatile("s_waitcnt lgkmcnt(0)" ::: "memory");   // wave-local LDS visibility

    // ---- in-wave projection: lane (o = ln>>2, q = ln&3) covers 128 dims ----
    // i-index rotated by 8*q so the 4 quad lanes hit different LDS banks.
    {
        const float* m = reinterpret_cast<const float*>(mw);
        const int o = ln >> 2;
        const int q = ln & 3;
        float p = 0.f;
        if (o < NOSC) {
#pragma unroll 16
            for (int i = 0; i < 128; ++i) {
                const int d = q * 128 + ((i + 8 * q) & 127);
                p += m[d] * W_in[d * NOSC + o];
            }
        }
        p = dpp_sum4(p);                 // full dot now in every lane of the quad
        if (q == 0) th0[wv][o] = (o < NOSC) ? (p + b_in[o]) : 0.f;
    }
    asm volatile("s_waitcnt lgkmcnt(0)" ::: "memory");

    // ---- 16-lane Kuramoto scan (all 4 lane-rows duplicate it; DPP is row-local)
    const int  o    = ln & 15;
    const bool act  = (o < NOSC);
    const float mask = act ? 1.0f : 0.0f;
    const int   oc   = act ? o : (NOSC - 1);

    float theta = th0[wv][o];
    const float drift = 6.283185307179586f * omega[oc];
    const float kn = 1.5f / (float)NOSC;
    const float dt = 0.01f;

    for (int it = 0; it < NSTEP; ++it) {
        float s_, c_;
        fast_sincos(theta, &s_, &c_);
        s_ *= mask; c_ *= mask;
        const float S = dpp_sum16(s_);
        const float C = dpp_sum16(c_);
        theta += dt * (drift + kn * (S * c_ - C * s_));
    }

    float hs, hc;
    fast_sincos(theta, &hs, &hc);
    const float h = hc * mask;
    float z0 = dpp_sum16(h * Wc[oc * 2 + 0]);
    float z1 = dpp_sum16(h * Wc[oc * 2 + 1]);

    if (ln == 0) {
        z0 += bc[0]; z1 += bc[1];
        const float mx  = fmaxf(z0, z1);
        const float lse = mx + logf(expf(z0 - mx) + expf(z1 - mx));
        float2 r = make_float2(z0 - lse, z1 - lse);
        *reinterpret_cast<float2*>(&out[(size_t)row * 2]) = r;
    }
}

extern "C" void kernel_launch(void* const* d_in, const int* in_sizes, int n_in,
                              void* d_out, int out_size, void* d_ws, size_t ws_size,
                              hipStream_t stream)
{
    const float* x     = (const float*)d_in[0];
    const float* W_in  = (const float*)d_in[1];
    const float* b_in  = (const float*)d_in[2];
    const float* omega = (const float*)d_in[3];
    const float* Wc    = (const float*)d_in[4];
    const float* bc    = (const float*)d_in[5];
    float* out = (float*)d_out;

    const int B = in_sizes[0] / (SEQ * DIM);   // 4096

    const int grid = (B + RPB - 1) / RPB;      // 1024 = 4 blocks/CU x 256 CU
    fused_kernel<<<grid, 256, 0, stream>>>(x, W_in, b_in, omega, Wc, bc, out, B);
}

// Round 9
// 109.556 us; speedup vs baseline: 1.0017x; 1.0017x over previous
//
#include <hip/hip_runtime.h>
#include <math.h>

#define SEQ   64
#define DIM   512
#define NOSC  14
#define NSTEP 100
#define RPB   4     // rows per block = waves per block (1 row per wave)

typedef float f4 __attribute__((ext_vector_type(4)));

// DPP sums (bound_ctrl=1). Patterns are local to each 16-lane row, so four
// independent 16-lane reductions coexist in one 64-lane wave.
__device__ __forceinline__ float dpp_sum4(float v) {   // sum within quad
    v += __int_as_float(__builtin_amdgcn_update_dpp(0, __float_as_int(v), 0xB1,  0xF, 0xF, true));
    v += __int_as_float(__builtin_amdgcn_update_dpp(0, __float_as_int(v), 0x4E,  0xF, 0xF, true));
    return v;
}
__device__ __forceinline__ float dpp_sum16(float v) {  // sum within 16-lane row
    v += __int_as_float(__builtin_amdgcn_update_dpp(0, __float_as_int(v), 0xB1,  0xF, 0xF, true));
    v += __int_as_float(__builtin_amdgcn_update_dpp(0, __float_as_int(v), 0x4E,  0xF, 0xF, true));
    v += __int_as_float(__builtin_amdgcn_update_dpp(0, __float_as_int(v), 0x141, 0xF, 0xF, true));
    v += __int_as_float(__builtin_amdgcn_update_dpp(0, __float_as_int(v), 0x140, 0xF, 0xF, true));
    return v;
}

// HW trig: v_sin_f32 / v_cos_f32 take REVOLUTIONS; reduce with fract first.
__device__ __forceinline__ void fast_sincos(float theta, float* s, float* c) {
    const float inv2pi = 0.15915494309189535f;
    float r = theta * inv2pi;
    r = r - floorf(r);
    *s = __builtin_amdgcn_sinf(r);
    *c = __builtin_amdgcn_cosf(r);
}

// Fully wave-independent: each 64-lane wave owns ONE row end-to-end.
// R8 A/B: identical to R7 except PLAIN loads (no nontemporal hint).
__global__ __launch_bounds__(256, 4)
void fused_kernel(const float* __restrict__ x,
                  const float* __restrict__ W_in,
                  const float* __restrict__ b_in,
                  const float* __restrict__ omega,
                  const float* __restrict__ Wc,
                  const float* __restrict__ bc,
                  float* __restrict__ out, int B)
{
    const int t   = threadIdx.x;
    const int wv  = t >> 6;
    const int ln  = t & 63;
    const int row = blockIdx.x * RPB + wv;

    __shared__ f4    mv[RPB][DIM / 4];   // per-wave private pooled row
    __shared__ float th0[RPB][16];       // per-wave theta0

    if (row >= B) return;                // uniform per wave

    // ---- load + pool: this wave reads its whole row (2 x f4 per token) ----
    const f4* xv = reinterpret_cast<const f4*>(x + (size_t)row * (SEQ * DIM));
    f4 a0 = (f4)(0.0f), a1 = (f4)(0.0f);
#pragma unroll 8
    for (int s = 0; s < SEQ; ++s) {
        a0 += xv[s * (DIM / 4) + ln];
        a1 += xv[s * (DIM / 4) + 64 + ln];
    }
    f4* mw = mv[wv];
    mw[ln]      = a0 * (1.0f / SEQ);
    mw[ln + 64] = a1 * (1.0f / SEQ);
    asm volatile("s_waitcnt lgkmcnt(0)" ::: "memory");   // wave-local LDS visibility

    // ---- in-wave projection: lane (o = ln>>2, q = ln&3) covers 128 dims ----
    // i-index rotated by 8*q so the 4 quad lanes hit different LDS banks.
    {
        const float* m = reinterpret_cast<const float*>(mw);
        const int o = ln >> 2;
        const int q = ln & 3;
        float p = 0.f;
        if (o < NOSC) {
#pragma unroll 16
            for (int i = 0; i < 128; ++i) {
                const int d = q * 128 + ((i + 8 * q) & 127);
                p += m[d] * W_in[d * NOSC + o];
            }
        }
        p = dpp_sum4(p);                 // full dot now in every lane of the quad
        if (q == 0) th0[wv][o] = (o < NOSC) ? (p + b_in[o]) : 0.f;
    }
    asm volatile("s_waitcnt lgkmcnt(0)" ::: "memory");

    // ---- 16-lane Kuramoto scan (all 4 lane-rows duplicate it; DPP is row-local)
    const int  o    = ln & 15;
    const bool act  = (o < NOSC);
    const float mask = act ? 1.0f : 0.0f;
    const int   oc   = act ? o : (NOSC - 1);

    float theta = th0[wv][o];
    const float drift = 6.283185307179586f * omega[oc];
    const float kn = 1.5f / (float)NOSC;
    const float dt = 0.01f;

    for (int it = 0; it < NSTEP; ++it) {
        float s_, c_;
        fast_sincos(theta, &s_, &c_);
        s_ *= mask; c_ *= mask;
        const float S = dpp_sum16(s_);
        const float C = dpp_sum16(c_);
        theta += dt * (drift + kn * (S * c_ - C * s_));
    }

    float hs, hc;
    fast_sincos(theta, &hs, &hc);
    const float h = hc * mask;
    float z0 = dpp_sum16(h * Wc[oc * 2 + 0]);
    float z1 = dpp_sum16(h * Wc[oc * 2 + 1]);

    if (ln == 0) {
        z0 += bc[0]; z1 += bc[1];
        const float mx  = fmaxf(z0, z1);
        const float lse = mx + logf(expf(z0 - mx) + expf(z1 - mx));
        float2 r = make_float2(z0 - lse, z1 - lse);
        *reinterpret_cast<float2*>(&out[(size_t)row * 2]) = r;
    }
}

extern "C" void kernel_launch(void* const* d_in, const int* in_sizes, int n_in,
                              void* d_out, int out_size, void* d_ws, size_t ws_size,
                              hipStream_t stream)
{
    const float* x     = (const float*)d_in[0];
    const float* W_in  = (const float*)d_in[1];
    const float* b_in  = (const float*)d_in[2];
    const float* omega = (const float*)d_in[3];
    const float* Wc    = (const float*)d_in[4];
    const float* bc    = (const float*)d_in[5];
    float* out = (float*)d_out;

    const int B = in_sizes[0] / (SEQ * DIM);   // 4096

    const int grid = (B + RPB - 1) / RPB;      // 1024 = 4 blocks/CU x 256 CU
    fused_kernel<<<grid, 256, 0, stream>>>(x, W_in, b_in, omega, Wc, bc, out, B);
}

// Round 10
// 98.376 us; speedup vs baseline: 1.1155x; 1.1137x over previous
//
#include <hip/hip_runtime.h>
#include <math.h>

#define SEQ   64
#define DIM   512
#define NOSC  14
#define NSTEP 100
#define RPB   4     // rows per block

typedef float f4 __attribute__((ext_vector_type(4)));

// 16-lane sum + broadcast using pure-VALU DPP:
//   quad_perm xor1 = 0xB1, xor2 = 0x4E, row_half_mirror = 0x141, row_mirror = 0x140
__device__ __forceinline__ float dpp_sum16(float v) {
    v += __int_as_float(__builtin_amdgcn_update_dpp(0, __float_as_int(v), 0xB1,  0xF, 0xF, true));
    v += __int_as_float(__builtin_amdgcn_update_dpp(0, __float_as_int(v), 0x4E,  0xF, 0xF, true));
    v += __int_as_float(__builtin_amdgcn_update_dpp(0, __float_as_int(v), 0x141, 0xF, 0xF, true));
    v += __int_as_float(__builtin_amdgcn_update_dpp(0, __float_as_int(v), 0x140, 0xF, 0xF, true));
    return v;
}

// HW trig: v_sin_f32 / v_cos_f32 take REVOLUTIONS; reduce with fract first.
__device__ __forceinline__ void fast_sincos(float theta, float* s, float* c) {
    const float inv2pi = 0.15915494309189535f;
    float r = theta * inv2pi;
    r = r - floorf(r);
    *s = __builtin_amdgcn_sinf(r);
    *c = __builtin_amdgcn_cosf(r);
}

// Fused, block-pipelined: each block owns RPB rows. (Best-measured config: R5.)
//   waves 0-1 (128 thr): load+pool row r+1 (1 float4 chunk per thread, 64 tokens)
//   wave 3 lanes 0-15:   Kuramoto scan + readout for row r (concurrently)
//   projection: 224 threads, between barriers. mv double-buffered.
// 4 blocks/CU (grid 1024), launch_bounds(256,4) -> 128 VGPR budget, unroll 8
// gives 8 in-flight float4 loads per thread. Nontemporal loads: A/B'd +9%.
__global__ __launch_bounds__(256, 4)
void fused_kernel(const float* __restrict__ x,
                  const float* __restrict__ W_in,
                  const float* __restrict__ b_in,
                  const float* __restrict__ omega,
                  const float* __restrict__ Wc,
                  const float* __restrict__ bc,
                  float* __restrict__ out, int B)
{
    const int t    = threadIdx.x;
    const int row0 = blockIdx.x * RPB;

    __shared__ f4    mv[2][DIM / 4];   // pooled mean vectors (double-buffered)
    __shared__ float pp[NOSC][16];     // projection partials

    // ---- prologue: load+pool row0 -> mv[0]
    if (t < 128 && row0 < B) {
        const f4* xv = reinterpret_cast<const f4*>(x + (size_t)row0 * (SEQ * DIM));
        f4 acc = (f4)(0.0f);
#pragma unroll 8
        for (int s = 0; s < SEQ; ++s)
            acc += __builtin_nontemporal_load(&xv[s * (DIM / 4) + t]);
        mv[0][t] = acc * (1.0f / SEQ);
    }
    __syncthreads();
    {   // ---- project row0 -> pp (conflict-free: 16 ch-lanes read consecutive floats)
        const float* m = reinterpret_cast<const float*>(mv[0]);
        if (t < NOSC * 16) {
            const int o  = t >> 4;
            const int ch = t & 15;
            float p = 0.f;
#pragma unroll 8
            for (int i = 0; i < 32; ++i) {
                const int d = i * 16 + ch;
                p += m[d] * W_in[d * NOSC + o];
            }
            pp[o][ch] = p;
        }
    }
    __syncthreads();

    for (int r = 0; r < RPB; ++r) {
        const int nb = (r & 1) ^ 1;    // buffer for next row
        if (t >= 192) {
            // ---- wave 3, lanes 0-15: scan row0+r while waves 0-1 load row r+1
            const int lane = t - 192;
            const int row  = row0 + r;
            if (lane < 16 && row < B) {
                const bool  act  = (lane < NOSC);
                const float mask = act ? 1.0f : 0.0f;
                const int   oc   = act ? lane : (NOSC - 1);

                float theta = 0.0f;
                if (act) {
                    theta = b_in[lane];
#pragma unroll
                    for (int ch = 0; ch < 16; ++ch) theta += pp[lane][ch];
                }
                const float drift = 6.283185307179586f * omega[oc];
                const float kn = 1.5f / (float)NOSC;
                const float dt = 0.01f;

                for (int it = 0; it < NSTEP; ++it) {
                    float s_, c_;
                    fast_sincos(theta, &s_, &c_);
                    s_ *= mask; c_ *= mask;
                    const float S = dpp_sum16(s_);
                    const float C = dpp_sum16(c_);
                    theta += dt * (drift + kn * (S * c_ - C * s_));
                }

                float hs, hc;
                fast_sincos(theta, &hs, &hc);
                const float h = hc * mask;
                float z0 = dpp_sum16(h * Wc[oc * 2 + 0]);
                float z1 = dpp_sum16(h * Wc[oc * 2 + 1]);
                if (lane == 0) {
                    z0 += bc[0]; z1 += bc[1];
                    const float mx  = fmaxf(z0, z1);
                    const float lse = mx + logf(expf(z0 - mx) + expf(z1 - mx));
                    out[(size_t)row * 2 + 0] = z0 - lse;
                    out[(size_t)row * 2 + 1] = z1 - lse;
                }
            }
        } else if (t < 128 && r + 1 < RPB && row0 + r + 1 < B) {
            // ---- waves 0-1: load+pool next row -> mv[nb]
            const f4* xv = reinterpret_cast<const f4*>(x + (size_t)(row0 + r + 1) * (SEQ * DIM));
            f4 acc = (f4)(0.0f);
#pragma unroll 8
            for (int s = 0; s < SEQ; ++s)
                acc += __builtin_nontemporal_load(&xv[s * (DIM / 4) + t]);
            mv[nb][t] = acc * (1.0f / SEQ);
        }
        __syncthreads();
        if (r + 1 < RPB) {
            // pp is free now (scan r finished before the barrier)
            const float* m = reinterpret_cast<const float*>(mv[nb]);
            if (t < NOSC * 16) {
                const int o  = t >> 4;
                const int ch = t & 15;
                float p = 0.f;
#pragma unroll 8
                for (int i = 0; i < 32; ++i) {
                    const int d = i * 16 + ch;
                    p += m[d] * W_in[d * NOSC + o];
                }
                pp[o][ch] = p;
            }
        }
        __syncthreads();
    }
}

extern "C" void kernel_launch(void* const* d_in, const int* in_sizes, int n_in,
                              void* d_out, int out_size, void* d_ws, size_t ws_size,
                              hipStream_t stream)
{
    const float* x     = (const float*)d_in[0];
    const float* W_in  = (const float*)d_in[1];
    const float* b_in  = (const float*)d_in[2];
    const float* omega = (const float*)d_in[3];
    const float* Wc    = (const float*)d_in[4];
    const float* bc    = (const float*)d_in[5];
    float* out = (float*)d_out;

    const int B = in_sizes[0] / (SEQ * DIM);   // 4096

    const int grid = (B + RPB - 1) / RPB;      // 1024 = 4 blocks/CU x 256 CU
    fused_kernel<<<grid, 256, 0, stream>>>(x, W_in, b_in, omega, Wc, bc, out, B);
}

// Round 12
// 98.298 us; speedup vs baseline: 1.1164x; 1.0008x over previous
//
#include <hip/hip_runtime.h>
#include <math.h>

#define SEQ   64
#define DIM   512
#define NOSC  14
#define NSTEP 100
#define RPB   4     // rows per block

typedef float f4 __attribute__((ext_vector_type(4)));

// 16-lane sum + broadcast using pure-VALU DPP:
//   quad_perm xor1 = 0xB1, xor2 = 0x4E, row_half_mirror = 0x141, row_mirror = 0x140
__device__ __forceinline__ float dpp_sum16(float v) {
    v += __int_as_float(__builtin_amdgcn_update_dpp(0, __float_as_int(v), 0xB1,  0xF, 0xF, true));
    v += __int_as_float(__builtin_amdgcn_update_dpp(0, __float_as_int(v), 0x4E,  0xF, 0xF, true));
    v += __int_as_float(__builtin_amdgcn_update_dpp(0, __float_as_int(v), 0x141, 0xF, 0xF, true));
    v += __int_as_float(__builtin_amdgcn_update_dpp(0, __float_as_int(v), 0x140, 0xF, 0xF, true));
    return v;
}

// HW trig: v_sin_f32 / v_cos_f32 take REVOLUTIONS; reduce with fract first.
__device__ __forceinline__ void fast_sincos(float theta, float* s, float* c) {
    const float inv2pi = 0.15915494309189535f;
    float r = theta * inv2pi;
    r = r - floorf(r);
    *s = __builtin_amdgcn_sinf(r);
    *c = __builtin_amdgcn_cosf(r);
}

// Fused, block-pipelined: each block owns RPB rows. (Best-measured config:
// R5/R10, 98.3/98.4 us.)
//   waves 0-1 (128 thr): load+pool row r+1 (1 float4 chunk per thread, 64 tokens)
//   wave 3 lanes 0-15:   Kuramoto scan + readout for row r (concurrently)
//   projection: 224 threads, between barriers. mv double-buffered.
// 4 blocks/CU (grid 1024), launch_bounds(256,4) -> 128 VGPR budget, unroll 8
// gives 8 in-flight float4 loads per thread. Nontemporal loads: A/B'd +9%.
__global__ __launch_bounds__(256, 4)
void fused_kernel(const float* __restrict__ x,
                  const float* __restrict__ W_in,
                  const float* __restrict__ b_in,
                  const float* __restrict__ omega,
                  const float* __restrict__ Wc,
                  const float* __restrict__ bc,
                  float* __restrict__ out, int B)
{
    const int t    = threadIdx.x;
    const int row0 = blockIdx.x * RPB;

    __shared__ f4    mv[2][DIM / 4];   // pooled mean vectors (double-buffered)
    __shared__ float pp[NOSC][16];     // projection partials

    // ---- prologue: load+pool row0 -> mv[0]
    if (t < 128 && row0 < B) {
        const f4* xv = reinterpret_cast<const f4*>(x + (size_t)row0 * (SEQ * DIM));
        f4 acc = (f4)(0.0f);
#pragma unroll 8
        for (int s = 0; s < SEQ; ++s)
            acc += __builtin_nontemporal_load(&xv[s * (DIM / 4) + t]);
        mv[0][t] = acc * (1.0f / SEQ);
    }
    __syncthreads();
    {   // ---- project row0 -> pp (conflict-free: 16 ch-lanes read consecutive floats)
        const float* m = reinterpret_cast<const float*>(mv[0]);
        if (t < NOSC * 16) {
            const int o  = t >> 4;
            const int ch = t & 15;
            float p = 0.f;
#pragma unroll 8
            for (int i = 0; i < 32; ++i) {
                const int d = i * 16 + ch;
                p += m[d] * W_in[d * NOSC + o];
            }
            pp[o][ch] = p;
        }
    }
    __syncthreads();

    for (int r = 0; r < RPB; ++r) {
        const int nb = (r & 1) ^ 1;    // buffer for next row
        if (t >= 192) {
            // ---- wave 3, lanes 0-15: scan row0+r while waves 0-1 load row r+1
            const int lane = t - 192;
            const int row  = row0 + r;
            if (lane < 16 && row < B) {
                const bool  act  = (lane < NOSC);
                const float mask = act ? 1.0f : 0.0f;
                const int   oc   = act ? lane : (NOSC - 1);

                float theta = 0.0f;
                if (act) {
                    theta = b_in[lane];
#pragma unroll
                    for (int ch = 0; ch < 16; ++ch) theta += pp[lane][ch];
                }
                const float drift = 6.283185307179586f * omega[oc];
                const float kn = 1.5f / (float)NOSC;
                const float dt = 0.01f;

                for (int it = 0; it < NSTEP; ++it) {
                    float s_, c_;
                    fast_sincos(theta, &s_, &c_);
                    s_ *= mask; c_ *= mask;
                    const float S = dpp_sum16(s_);
                    const float C = dpp_sum16(c_);
                    theta += dt * (drift + kn * (S * c_ - C * s_));
                }

                float hs, hc;
                fast_sincos(theta, &hs, &hc);
                const float h = hc * mask;
                float z0 = dpp_sum16(h * Wc[oc * 2 + 0]);
                float z1 = dpp_sum16(h * Wc[oc * 2 + 1]);
                if (lane == 0) {
                    z0 += bc[0]; z1 += bc[1];
                    const float mx  = fmaxf(z0, z1);
                    const float lse = mx + logf(expf(z0 - mx) + expf(z1 - mx));
                    out[(size_t)row * 2 + 0] = z0 - lse;
                    out[(size_t)row * 2 + 1] = z1 - lse;
                }
            }
        } else if (t < 128 && r + 1 < RPB && row0 + r + 1 < B) {
            // ---- waves 0-1: load+pool next row -> mv[nb]
            const f4* xv = reinterpret_cast<const f4*>(x + (size_t)(row0 + r + 1) * (SEQ * DIM));
            f4 acc = (f4)(0.0f);
#pragma unroll 8
            for (int s = 0; s < SEQ; ++s)
                acc += __builtin_nontemporal_load(&xv[s * (DIM / 4) + t]);
            mv[nb][t] = acc * (1.0f / SEQ);
        }
        __syncthreads();
        if (r + 1 < RPB) {
            // pp is free now (scan r finished before the barrier)
            const float* m = reinterpret_cast<const float*>(mv[nb]);
            if (t < NOSC * 16) {
                const int o  = t >> 4;
                const int ch = t & 15;
                float p = 0.f;
#pragma unroll 8
                for (int i = 0; i < 32; ++i) {
                    const int d = i * 16 + ch;
                    p += m[d] * W_in[d * NOSC + o];
                }
                pp[o][ch] = p;
            }
        }
        __syncthreads();
    }
}

extern "C" void kernel_launch(void* const* d_in, const int* in_sizes, int n_in,
                              void* d_out, int out_size, void* d_ws, size_t ws_size,
                              hipStream_t stream)
{
    const float* x     = (const float*)d_in[0];
    const float* W_in  = (const float*)d_in[1];
    const float* b_in  = (const float*)d_in[2];
    const float* omega = (const float*)d_in[3];
    const float* Wc    = (const float*)d_in[4];
    const float* bc    = (const float*)d_in[5];
    float* out = (float*)d_out;

    const int B = in_sizes[0] / (SEQ * DIM);   // 4096

    const int grid = (B + RPB - 1) / RPB;      // 1024 = 4 blocks/CU x 256 CU
    fused_kernel<<<grid, 256, 0, stream>>>(x, W_in, b_in, omega, Wc, bc, out, B);
}